// Round 3
// baseline (417.364 us; speedup 1.0000x reference)
//
#include <hip/hip_runtime.h>

#define NH 32   // S-box hidden width

// XOR-of-3 parity gadget: relu(s) - 2relu(s-1) + 2relu(s-2) - 2relu(s-3)
__device__ __forceinline__ float mixg(float s) {
    float t0 = fmaxf(s, 0.f);
    float t1 = fmaxf(s - 1.f, 0.f);
    float t2 = fmaxf(s - 2.f, 0.f);
    float t3 = fmaxf(s - 3.f, 0.f);
    return t0 - 2.f * (t1 - t2 + t3);
}

struct alignas(16) SW {
    float w0[NH][8];      // sbox_w0 row-major
    float w1t[NH][8];     // sbox_w1 transposed [h][j]
    float b0[NH];         // sbox_b0
    float pad[24];
    float t0[11 * 128];   // w01*k + xb0 per (round,pos)
    float t1[11 * 128];   // w11*k + xb1 per (round,pos)
};

// SubBytes on 8 of the 16 bytes (columns J0, J0+1), hidden-unit-major so each
// weight-row LDS broadcast is amortized over 8 bytes. All st indices are
// compile-time so st stays in VGPRs.
template<int J0>
__device__ __forceinline__ void sub_group(float (&st)[4][4][8], const SW& sw)
{
    float acc[4][2][8];
    #pragma unroll
    for (int i = 0; i < 4; ++i)
        #pragma unroll
        for (int jj = 0; jj < 2; ++jj)
            #pragma unroll
            for (int k = 0; k < 8; ++k) acc[i][jj][k] = 0.f;

    for (int h = 0; h < NH; ++h) {
        float4 wa = *(const float4*)&sw.w0[h][0];
        float4 wb = *(const float4*)&sw.w0[h][4];
        float4 va = *(const float4*)&sw.w1t[h][0];
        float4 vb = *(const float4*)&sw.w1t[h][4];
        float bb = sw.b0[h];
        float wr[8] = {wa.x, wa.y, wa.z, wa.w, wb.x, wb.y, wb.z, wb.w};
        float vr[8] = {va.x, va.y, va.z, va.w, vb.x, vb.y, vb.z, vb.w};
        #pragma unroll
        for (int i = 0; i < 4; ++i) {
            #pragma unroll
            for (int jj = 0; jj < 2; ++jj) {
                float hv = bb;
                #pragma unroll
                for (int k = 0; k < 8; ++k) hv = fmaf(wr[k], st[i][J0 + jj][k], hv);
                hv = fmaxf(hv, 0.f);
                #pragma unroll
                for (int k = 0; k < 8; ++k) acc[i][jj][k] = fmaf(vr[k], hv, acc[i][jj][k]);
            }
        }
    }
    #pragma unroll
    for (int i = 0; i < 4; ++i)
        #pragma unroll
        for (int jj = 0; jj < 2; ++jj)
            #pragma unroll
            for (int k = 0; k < 8; ++k) st[i][J0 + jj][k] = acc[i][jj][k];
}

__global__ __launch_bounds__(256, 2) void neural_aes_kernel(
    const float* __restrict__ st_in,   // [B,128]
    const float* __restrict__ rk,      // [11,1,4,4,8]
    const float* __restrict__ xw,      // [2,2]
    const float* __restrict__ xb,      // [2]
    const float* __restrict__ w0,      // [32,8]
    const float* __restrict__ b0,      // [32]
    const float* __restrict__ w1,      // [8,32]
    float* __restrict__ out, int B)
{
    __shared__ SW sw;
    const int tid = threadIdx.x;
    const float w00 = xw[0], w01 = xw[1], w10 = xw[2], w11 = xw[3];
    const float xb0 = xb[0], xb1 = xb[1];

    // Stage S-box weights (w1 transposed) into LDS
    for (int idx = tid; idx < NH * 8; idx += 256) {
        int h = idx >> 3, k = idx & 7;
        sw.w0[h][k]  = w0[idx];
        sw.w1t[h][k] = w1[k * NH + h];
    }
    if (tid < NH) sw.b0[tid] = b0[tid];
    // Precompute key-dependent ARK terms: ark(s,k) = relu(w00*s + t0) + relu(w10*s + t1)
    for (int idx = tid; idx < 11 * 128; idx += 256) {
        float kv = rk[idx];
        sw.t0[idx] = fmaf(w01, kv, xb0);
        sw.t1[idx] = fmaf(w11, kv, xb1);
    }
    __syncthreads();

    const int b = blockIdx.x * 256 + tid;
    if (b >= B) return;
    const float* __restrict__ inp = st_in + (size_t)b * 128;
    float* __restrict__ op = out + (size_t)b * 128;

    // st[i][j][k] = input[j*32 + i*8 + k]  (reshape(4,4,8).swapaxes(1,2))
    float st[4][4][8];

    // Load + initial ARK (round key 0)
    #pragma unroll
    for (int j = 0; j < 4; ++j) {
        #pragma unroll
        for (int i = 0; i < 4; ++i) {
            float4 a = *(const float4*)(inp + j * 32 + i * 8);
            float4 c = *(const float4*)(inp + j * 32 + i * 8 + 4);
            float xv[8] = {a.x, a.y, a.z, a.w, c.x, c.y, c.z, c.w};
            #pragma unroll
            for (int k = 0; k < 8; ++k) {
                float t0v = sw.t0[i * 32 + j * 8 + k];
                float t1v = sw.t1[i * 32 + j * 8 + k];
                float c0 = fmaf(w00, xv[k], t0v);
                float c1 = fmaf(w10, xv[k], t1v);
                st[i][j][k] = fmaxf(c0, 0.f) + fmaxf(c1, 0.f);
            }
        }
    }

    // Rounds 1..9: SubBytes, ShiftRows+MixColumns (fused), ARK
    for (int r = 1; r <= 9; ++r) {
        sub_group<0>(st, sw);
        sub_group<2>(st, sw);

        // ShiftRows folded into MixColumns' source indices:
        // shifted[i][j] = sb[(i+j)&3][j];  mix rolls along j (axis 2)
        #pragma unroll
        for (int k = 0; k < 8; ++k) {
            float ns[4][4];
            #pragma unroll
            for (int i = 0; i < 4; ++i) {
                #pragma unroll
                for (int j = 0; j < 4; ++j) {
                    float s = st[(i + j) & 3][j][k]
                            + st[(i + j + 1) & 3][(j + 1) & 3][k]
                            + st[(i + j + 2) & 3][(j + 2) & 3][k];
                    ns[i][j] = mixg(s);
                }
            }
            #pragma unroll
            for (int i = 0; i < 4; ++i)
                #pragma unroll
                for (int j = 0; j < 4; ++j) st[i][j][k] = ns[i][j];
        }

        // ARK round r
        const float* t0p = sw.t0 + r * 128;
        const float* t1p = sw.t1 + r * 128;
        #pragma unroll
        for (int i = 0; i < 4; ++i) {
            #pragma unroll
            for (int j = 0; j < 4; ++j) {
                float4 ta = *(const float4*)(t0p + i * 32 + j * 8);
                float4 tb = *(const float4*)(t0p + i * 32 + j * 8 + 4);
                float4 ua = *(const float4*)(t1p + i * 32 + j * 8);
                float4 ub = *(const float4*)(t1p + i * 32 + j * 8 + 4);
                float tr0[8] = {ta.x, ta.y, ta.z, ta.w, tb.x, tb.y, tb.z, tb.w};
                float tr1[8] = {ua.x, ua.y, ua.z, ua.w, ub.x, ub.y, ub.z, ub.w};
                #pragma unroll
                for (int k = 0; k < 8; ++k) {
                    float c0 = fmaf(w00, st[i][j][k], tr0[k]);
                    float c1 = fmaf(w10, st[i][j][k], tr1[k]);
                    st[i][j][k] = fmaxf(c0, 0.f) + fmaxf(c1, 0.f);
                }
            }
        }
    }

    // Final round: SubBytes, then ShiftRows + ARK(rk[10]) folded into the store
    sub_group<0>(st, sw);
    sub_group<2>(st, sw);
    const float* t0p = sw.t0 + 10 * 128;
    const float* t1p = sw.t1 + 10 * 128;
    #pragma unroll
    for (int j = 0; j < 4; ++j) {
        #pragma unroll
        for (int i = 0; i < 4; ++i) {
            float4 ta = *(const float4*)(t0p + i * 32 + j * 8);
            float4 tb = *(const float4*)(t0p + i * 32 + j * 8 + 4);
            float4 ua = *(const float4*)(t1p + i * 32 + j * 8);
            float4 ub = *(const float4*)(t1p + i * 32 + j * 8 + 4);
            float tr0[8] = {ta.x, ta.y, ta.z, ta.w, tb.x, tb.y, tb.z, tb.w};
            float tr1[8] = {ua.x, ua.y, ua.z, ua.w, ub.x, ub.y, ub.z, ub.w};
            float v[8];
            #pragma unroll
            for (int k = 0; k < 8; ++k) {
                float x = st[(i + j) & 3][j][k];   // ShiftRows
                float c0 = fmaf(w00, x, tr0[k]);
                float c1 = fmaf(w10, x, tr1[k]);
                v[k] = fmaxf(c0, 0.f) + fmaxf(c1, 0.f);
            }
            float4 oa = {v[0], v[1], v[2], v[3]};
            float4 oc = {v[4], v[5], v[6], v[7]};
            *(float4*)(op + j * 32 + i * 8) = oa;
            *(float4*)(op + j * 32 + i * 8 + 4) = oc;
        }
    }
}

extern "C" void kernel_launch(void* const* d_in, const int* in_sizes, int n_in,
                              void* d_out, int out_size, void* d_ws, size_t ws_size,
                              hipStream_t stream) {
    const float* st_in = (const float*)d_in[0];
    const float* rk    = (const float*)d_in[1];
    const float* xw    = (const float*)d_in[2];
    const float* xb    = (const float*)d_in[3];
    const float* w0    = (const float*)d_in[4];
    const float* b0    = (const float*)d_in[5];
    const float* w1    = (const float*)d_in[6];
    float* out = (float*)d_out;
    const int B = in_sizes[0] / 128;
    const int grid = (B + 255) / 256;
    neural_aes_kernel<<<grid, 256, 0, stream>>>(st_in, rk, xw, xb, w0, b0, w1, out, B);
}